// Round 1
// baseline (493.234 us; speedup 1.0000x reference)
//
#include <hip/hip_runtime.h>

#define NN 50000
#define NE 800000
#define EH (NE + NN)   // 850000 edges incl. self-loops
#define HD 128

// ---------------- degree / CSR build ----------------
__global__ void k_init_deg(int* __restrict__ deg) {
  int i = blockIdx.x * 256 + threadIdx.x;
  if (i < NN) deg[i] = 1;   // self-loop contributes 1
}

__global__ void k_count(const int* __restrict__ dst, int* __restrict__ deg) {
  int e = blockIdx.x * 256 + threadIdx.x;
  if (e < NE) atomicAdd(&deg[dst[e]], 1);
}

__global__ void k_dis(const int* __restrict__ deg, float* __restrict__ dis) {
  int i = blockIdx.x * 256 + threadIdx.x;
  if (i < NN) dis[i] = rsqrtf((float)deg[i]);   // deg >= 1 always
}

// single-block chunked exclusive scan over deg -> row_start; also seeds cursor
__global__ __launch_bounds__(1024) void k_scan(const int* __restrict__ deg,
                                               int* __restrict__ row_start,
                                               int* __restrict__ cursor) {
  __shared__ int lds[1024];
  const int CH = (NN + 1023) / 1024;   // 49
  int t = threadIdx.x;
  int s = t * CH;
  int e = s + CH; if (e > NN) e = NN;
  int sum = 0;
  for (int i = s; i < e; ++i) sum += deg[i];
  lds[t] = sum;
  __syncthreads();
  for (int off = 1; off < 1024; off <<= 1) {
    int v = (t >= off) ? lds[t - off] : 0;
    __syncthreads();
    lds[t] += v;
    __syncthreads();
  }
  int run = lds[t] - sum;              // exclusive prefix of this chunk
  for (int i = s; i < e; ++i) {
    row_start[i] = run; cursor[i] = run; run += deg[i];
  }
  if (t == 1023) row_start[NN] = lds[1023];
}

__global__ void k_fill(const int* __restrict__ src, const int* __restrict__ dst,
                       int* __restrict__ cursor, int* __restrict__ csr_src) {
  int e = blockIdx.x * 256 + threadIdx.x;
  if (e >= EH) return;
  int s, d;
  if (e < NE) { s = src[e]; d = dst[e]; }
  else        { s = e - NE; d = s; }          // self-loop
  int pos = atomicAdd(&cursor[d], 1);
  csr_src[pos] = s;
}

// ---------------- dense GEMM: C[NN,128] = A[NN,128] @ W[128,128] ----------------
#define GR 128
__global__ __launch_bounds__(256, 1) void k_gemm(const float* __restrict__ A,
                                                 const float* __restrict__ W,
                                                 float* __restrict__ C) {
  __shared__ float As[GR][HD + 4];   // [row][k], +4 keeps 16B alignment, breaks worst conflicts
  __shared__ float Ws[HD * HD];      // [k][col]
  const int tid = threadIdx.x;
  const int r0 = blockIdx.x * GR;
  // stage W (4096 float4)
  #pragma unroll
  for (int m = 0; m < 16; ++m) {
    int f = tid + m * 256;
    ((float4*)Ws)[f] = ((const float4*)W)[f];
  }
  // stage A tile (4096 float4)
  #pragma unroll
  for (int m = 0; m < 16; ++m) {
    int f = tid + m * 256;
    int r = f >> 5, c4 = f & 31;
    int gr_ = r0 + r;
    float4 v = make_float4(0.f, 0.f, 0.f, 0.f);
    if (gr_ < NN) v = ((const float4*)A)[gr_ * 32 + c4];
    *(float4*)&As[r][c4 * 4] = v;
  }
  __syncthreads();
  const int tg = tid >> 4;   // 0..15: rows tg, tg+16, ..., tg+112 (conflict-free stride)
  const int tc = tid & 15;   // cols tc*4..+3 and +64
  const int cc = tc * 4;
  float acc[8][8];
  #pragma unroll
  for (int j = 0; j < 8; ++j)
    #pragma unroll
    for (int c = 0; c < 8; ++c) acc[j][c] = 0.f;

  for (int k = 0; k < HD; k += 4) {
    float4 a[8];
    #pragma unroll
    for (int j = 0; j < 8; ++j) a[j] = *(const float4*)&As[tg + 16 * j][k];
    #pragma unroll
    for (int kk = 0; kk < 4; ++kk) {
      float4 w0 = *(const float4*)&Ws[(k + kk) * HD + cc];
      float4 w1 = *(const float4*)&Ws[(k + kk) * HD + cc + 64];
      #pragma unroll
      for (int j = 0; j < 8; ++j) {
        float av = (kk == 0) ? a[j].x : (kk == 1) ? a[j].y : (kk == 2) ? a[j].z : a[j].w;
        acc[j][0] += av * w0.x; acc[j][1] += av * w0.y;
        acc[j][2] += av * w0.z; acc[j][3] += av * w0.w;
        acc[j][4] += av * w1.x; acc[j][5] += av * w1.y;
        acc[j][6] += av * w1.z; acc[j][7] += av * w1.w;
      }
    }
  }
  #pragma unroll
  for (int j = 0; j < 8; ++j) {
    int row = r0 + tg + 16 * j;
    if (row < NN) {
      *(float4*)&C[row * HD + cc]      = make_float4(acc[j][0], acc[j][1], acc[j][2], acc[j][3]);
      *(float4*)&C[row * HD + cc + 64] = make_float4(acc[j][4], acc[j][5], acc[j][6], acc[j][7]);
    }
  }
}

// ---------------- CSR gather-aggregate + bias + LeakyReLU ----------------
// out[n,:] = leaky( dis[n] * sum_{e: dst=n} dis[src_e] * T[src_e,:] + b )
__global__ __launch_bounds__(256) void k_agg(const float* __restrict__ T,
                                             const float* __restrict__ dis,
                                             const int* __restrict__ row_start,
                                             const int* __restrict__ csr_src,
                                             const float* __restrict__ bias,
                                             float* __restrict__ out) {
  const int tid = threadIdx.x;
  const int n = blockIdx.x * 2 + (tid >> 7);   // 2 nodes per block
  const int col = tid & 127;
  if (n >= NN) return;
  const int rs = row_start[n], re = row_start[n + 1];
  float acc = 0.f;
  int j = rs;
  for (; j + 1 < re; j += 2) {
    int s0 = csr_src[j], s1 = csr_src[j + 1];
    float w0 = dis[s0], w1 = dis[s1];
    float t0 = T[s0 * HD + col];
    float t1 = T[s1 * HD + col];
    acc += w0 * t0;
    acc += w1 * t1;
  }
  if (j < re) {
    int s = csr_src[j];
    acc += dis[s] * T[s * HD + col];
  }
  float v = acc * dis[n] + bias[col];
  out[n * HD + col] = (v >= 0.f) ? v : 0.01f * v;
}

extern "C" void kernel_launch(void* const* d_in, const int* in_sizes, int n_in,
                              void* d_out, int out_size, void* d_ws, size_t ws_size,
                              hipStream_t stream) {
  const float* x  = (const float*)d_in[0];
  const int*   ei = (const int*)d_in[1];
  const float* W0 = (const float*)d_in[2];
  const float* b0 = (const float*)d_in[3];
  const float* W1 = (const float*)d_in[4];
  const float* b1 = (const float*)d_in[5];
  float* out = (float*)d_out;
  const int* src = ei;        // edge_index[0] = message source
  const int* dst = ei + NE;   // edge_index[1] = aggregation target

  char* p = (char*)d_ws;
  int*   deg       = (int*)p;    p += 50048 * 4;
  float* dis       = (float*)p;  p += 50048 * 4;
  int*   row_start = (int*)p;    p += 50052 * 4;
  int*   cursor    = (int*)p;    p += 50048 * 4;
  int*   csr       = (int*)p;    p += 850048 * 4;
  float* bufA      = (float*)p;  // 6,400,000 floats (25.6 MB); total ws use ~29.8 MB

  // graph build (once, reused by both layers)
  k_init_deg<<<196, 256, 0, stream>>>(deg);
  k_count<<<3125, 256, 0, stream>>>(dst, deg);
  k_dis<<<196, 256, 0, stream>>>(deg, dis);
  k_scan<<<1, 1024, 0, stream>>>(deg, row_start, cursor);
  k_fill<<<(EH + 255) / 256, 256, 0, stream>>>(src, dst, cursor, csr);

  // layer 1: t0 = x@W0 ; out = leaky(agg(t0) + b0)
  k_gemm<<<(NN + GR - 1) / GR, 256, 0, stream>>>(x, W0, bufA);
  k_agg<<<NN / 2, 256, 0, stream>>>(bufA, dis, row_start, csr, b0, out);
  // layer 2: t1 = out@W1 ; out = leaky(agg(t1) + b1)
  k_gemm<<<(NN + GR - 1) / GR, 256, 0, stream>>>(out, W1, bufA);
  k_agg<<<NN / 2, 256, 0, stream>>>(bufA, dis, row_start, csr, b1, out);
}

// Round 2
// 342.271 us; speedup vs baseline: 1.4411x; 1.4411x over previous
//
#include <hip/hip_runtime.h>

#define NN 50000
#define NE 800000
#define EH (NE + NN)   // 850000 edges incl. self-loops
#define HD 128
#define NB 196         // ceil(NN/256)

// ---------------- degree / CSR build ----------------
__global__ void k_init_deg(int* __restrict__ deg) {
  int i = blockIdx.x * 256 + threadIdx.x;
  if (i < NN) deg[i] = 1;   // self-loop contributes 1
}

__global__ void k_count(const int* __restrict__ dst, int* __restrict__ deg) {
  int e = blockIdx.x * 256 + threadIdx.x;
  if (e < NE) atomicAdd(&deg[dst[e]], 1);
}

// stage 1: per-block sums of deg
__global__ __launch_bounds__(256) void k_partial(const int* __restrict__ deg,
                                                 int* __restrict__ partial) {
  int i = blockIdx.x * 256 + threadIdx.x;
  int v = (i < NN) ? deg[i] : 0;
  #pragma unroll
  for (int off = 32; off >= 1; off >>= 1) v += __shfl_down(v, off);
  __shared__ int ws[4];
  if ((threadIdx.x & 63) == 0) ws[threadIdx.x >> 6] = v;
  __syncthreads();
  if (threadIdx.x == 0) partial[blockIdx.x] = ws[0] + ws[1] + ws[2] + ws[3];
}

// stage 2: exclusive scan of the 196 partials (single small block)
__global__ __launch_bounds__(256) void k_scanp(int* __restrict__ partial) {
  __shared__ int lds[256];
  int t = threadIdx.x;
  int v = (t < NB) ? partial[t] : 0;
  lds[t] = v;
  __syncthreads();
  #pragma unroll
  for (int off = 1; off < 256; off <<= 1) {
    int u = (t >= off) ? lds[t - off] : 0;
    __syncthreads();
    lds[t] += u;
    __syncthreads();
  }
  if (t < NB) partial[t] = lds[t] - v;   // exclusive
}

// stage 3: in-block exclusive scan + block offset -> row_start/cursor; fused dis=rsqrt(deg)
__global__ __launch_bounds__(256) void k_scatter(const int* __restrict__ deg,
                                                 const int* __restrict__ partial,
                                                 int* __restrict__ row_start,
                                                 int* __restrict__ cursor,
                                                 float* __restrict__ dis) {
  __shared__ int lds[256];
  int t = threadIdx.x;
  int i = blockIdx.x * 256 + t;
  int v = (i < NN) ? deg[i] : 0;
  lds[t] = v;
  __syncthreads();
  #pragma unroll
  for (int off = 1; off < 256; off <<= 1) {
    int u = (t >= off) ? lds[t - off] : 0;
    __syncthreads();
    lds[t] += u;
    __syncthreads();
  }
  int ex = lds[t] - v + partial[blockIdx.x];
  if (i < NN) {
    row_start[i] = ex;
    cursor[i] = ex;
    dis[i] = rsqrtf((float)v);   // v = deg[i] >= 1 always
    if (i == NN - 1) row_start[NN] = ex + v;
  }
}

__global__ void k_fill(const int* __restrict__ src, const int* __restrict__ dst,
                       int* __restrict__ cursor, int* __restrict__ csr_src) {
  int e = blockIdx.x * 256 + threadIdx.x;
  if (e >= EH) return;
  int s, d;
  if (e < NE) { s = src[e]; d = dst[e]; }
  else        { s = e - NE; d = s; }          // self-loop
  int pos = atomicAdd(&cursor[d], 1);
  csr_src[pos] = s;
}

// ---------------- dense GEMM: C[NN,128] = A[NN,128] @ W[128,128] ----------------
#define GR 128
__global__ __launch_bounds__(256, 1) void k_gemm(const float* __restrict__ A,
                                                 const float* __restrict__ W,
                                                 float* __restrict__ C) {
  __shared__ float As[GR][HD + 4];
  __shared__ float Ws[HD * HD];
  const int tid = threadIdx.x;
  const int r0 = blockIdx.x * GR;
  #pragma unroll
  for (int m = 0; m < 16; ++m) {
    int f = tid + m * 256;
    ((float4*)Ws)[f] = ((const float4*)W)[f];
  }
  #pragma unroll
  for (int m = 0; m < 16; ++m) {
    int f = tid + m * 256;
    int r = f >> 5, c4 = f & 31;
    int gr_ = r0 + r;
    float4 v = make_float4(0.f, 0.f, 0.f, 0.f);
    if (gr_ < NN) v = ((const float4*)A)[gr_ * 32 + c4];
    *(float4*)&As[r][c4 * 4] = v;
  }
  __syncthreads();
  const int tg = tid >> 4;
  const int tc = tid & 15;
  const int cc = tc * 4;
  float acc[8][8];
  #pragma unroll
  for (int j = 0; j < 8; ++j)
    #pragma unroll
    for (int c = 0; c < 8; ++c) acc[j][c] = 0.f;

  for (int k = 0; k < HD; k += 4) {
    float4 a[8];
    #pragma unroll
    for (int j = 0; j < 8; ++j) a[j] = *(const float4*)&As[tg + 16 * j][k];
    #pragma unroll
    for (int kk = 0; kk < 4; ++kk) {
      float4 w0 = *(const float4*)&Ws[(k + kk) * HD + cc];
      float4 w1 = *(const float4*)&Ws[(k + kk) * HD + cc + 64];
      #pragma unroll
      for (int j = 0; j < 8; ++j) {
        float av = (kk == 0) ? a[j].x : (kk == 1) ? a[j].y : (kk == 2) ? a[j].z : a[j].w;
        acc[j][0] += av * w0.x; acc[j][1] += av * w0.y;
        acc[j][2] += av * w0.z; acc[j][3] += av * w0.w;
        acc[j][4] += av * w1.x; acc[j][5] += av * w1.y;
        acc[j][6] += av * w1.z; acc[j][7] += av * w1.w;
      }
    }
  }
  #pragma unroll
  for (int j = 0; j < 8; ++j) {
    int row = r0 + tg + 16 * j;
    if (row < NN) {
      *(float4*)&C[row * HD + cc]      = make_float4(acc[j][0], acc[j][1], acc[j][2], acc[j][3]);
      *(float4*)&C[row * HD + cc + 64] = make_float4(acc[j][4], acc[j][5], acc[j][6], acc[j][7]);
    }
  }
}

// ---------------- CSR gather-aggregate + bias + LeakyReLU ----------------
// out[n,:] = leaky( dis[n] * sum_{e: dst=n} dis[src_e] * T[src_e,:] + b )
__global__ __launch_bounds__(256) void k_agg(const float* __restrict__ T,
                                             const float* __restrict__ dis,
                                             const int* __restrict__ row_start,
                                             const int* __restrict__ csr_src,
                                             const float* __restrict__ bias,
                                             float* __restrict__ out) {
  const int tid = threadIdx.x;
  const int n = blockIdx.x * 2 + (tid >> 7);   // 2 nodes per block
  const int col = tid & 127;
  if (n >= NN) return;
  const int rs = row_start[n], re = row_start[n + 1];
  float acc = 0.f;
  int j = rs;
  // 4-wide unroll: 4 outstanding gathers per iter to hide L2 latency
  for (; j + 3 < re; j += 4) {
    int s0 = csr_src[j], s1 = csr_src[j + 1], s2 = csr_src[j + 2], s3 = csr_src[j + 3];
    float w0 = dis[s0], w1 = dis[s1], w2 = dis[s2], w3 = dis[s3];
    float t0 = T[s0 * HD + col];
    float t1 = T[s1 * HD + col];
    float t2 = T[s2 * HD + col];
    float t3 = T[s3 * HD + col];
    acc += w0 * t0; acc += w1 * t1; acc += w2 * t2; acc += w3 * t3;
  }
  for (; j < re; ++j) {
    int s = csr_src[j];
    acc += dis[s] * T[s * HD + col];
  }
  float v = acc * dis[n] + bias[col];
  out[n * HD + col] = (v >= 0.f) ? v : 0.01f * v;
}

extern "C" void kernel_launch(void* const* d_in, const int* in_sizes, int n_in,
                              void* d_out, int out_size, void* d_ws, size_t ws_size,
                              hipStream_t stream) {
  const float* x  = (const float*)d_in[0];
  const int*   ei = (const int*)d_in[1];
  const float* W0 = (const float*)d_in[2];
  const float* b0 = (const float*)d_in[3];
  const float* W1 = (const float*)d_in[4];
  const float* b1 = (const float*)d_in[5];
  float* out = (float*)d_out;
  const int* src = ei;        // edge_index[0] = message source
  const int* dst = ei + NE;   // edge_index[1] = aggregation target

  char* p = (char*)d_ws;
  int*   deg       = (int*)p;    p += 50048 * 4;
  float* dis       = (float*)p;  p += 50048 * 4;
  int*   row_start = (int*)p;    p += 50052 * 4;
  int*   cursor    = (int*)p;    p += 50048 * 4;
  int*   partial   = (int*)p;    p += 256 * 4;
  int*   csr       = (int*)p;    p += 850048 * 4;
  float* bufA      = (float*)p;  // 6,400,000 floats (25.6 MB)

  // graph build (once, reused by both layers)
  k_init_deg<<<196, 256, 0, stream>>>(deg);
  k_count<<<3125, 256, 0, stream>>>(dst, deg);
  k_partial<<<NB, 256, 0, stream>>>(deg, partial);
  k_scanp<<<1, 256, 0, stream>>>(partial);
  k_scatter<<<NB, 256, 0, stream>>>(deg, partial, row_start, cursor, dis);
  k_fill<<<(EH + 255) / 256, 256, 0, stream>>>(src, dst, cursor, csr);

  // layer 1: t0 = x@W0 ; out = leaky(agg(t0) + b0)
  k_gemm<<<(NN + GR - 1) / GR, 256, 0, stream>>>(x, W0, bufA);
  k_agg<<<NN / 2, 256, 0, stream>>>(bufA, dis, row_start, csr, b0, out);
  // layer 2: t1 = out@W1 ; out = leaky(agg(t1) + b1)
  k_gemm<<<(NN + GR - 1) / GR, 256, 0, stream>>>(out, W1, bufA);
  k_agg<<<NN / 2, 256, 0, stream>>>(bufA, dis, row_start, csr, b1, out);
}